// Round 3
// baseline (1729.062 us; speedup 1.0000x reference)
//
#include <hip/hip_runtime.h>
#include <cstdint>
#include <cstddef>

// ---------------------------------------------------------------------------
// SwinV2 block, MI355X bf16-MFMA implementation.
// Round 3: barrier-free single-wave GEMM blocks, wave-private LDS dbuf,
// counted vmcnt(8) pipeline (never 0 in loop), T2 XOR-swizzled LDS reads
// with inverse-swizzled gll16 global sources. Attn: barriers -> lgkmcnt(0).
// ---------------------------------------------------------------------------

typedef unsigned short u16;
typedef __bf16 bf16x8 __attribute__((ext_vector_type(8)));
typedef float f32x4 __attribute__((ext_vector_type(4)));

#define VMW8 asm volatile("s_waitcnt vmcnt(8)" ::: "memory")
#define VMW0 asm volatile("s_waitcnt vmcnt(0)" ::: "memory")
#define LGKM0 asm volatile("s_waitcnt lgkmcnt(0)" ::: "memory")

__device__ __forceinline__ u16 f2bf(float f) {
  unsigned u = __builtin_bit_cast(unsigned, f);
  u += 0x7fffu + ((u >> 16) & 1u);
  return (u16)(u >> 16);
}

// async global->LDS, 16 bytes per lane; lane i's 16B land at base + i*16.
__device__ __forceinline__ void gll16(const u16* g, u16* l) {
  __builtin_amdgcn_global_load_lds(
      (const __attribute__((address_space(1))) void*)g,
      (__attribute__((address_space(3))) void*)l, 16, 0, 0);
}

// ---------------- diagnostics: ws too small sentinel ----------------
__global__ __launch_bounds__(256) void fill_k(float* o, int n) {
  int i = blockIdx.x * 256 + threadIdx.x;
  if (i < n) o[i] = 12345.0f;
}

// ---------------- weight convert + transpose (fp32 [K][N] -> bf16 [N][K]) ----
__global__ __launch_bounds__(256) void wconv_k(
    const float* __restrict__ qkv_w, const float* __restrict__ proj_w,
    const float* __restrict__ mlp_w1, const float* __restrict__ mlp_w2,
    u16* __restrict__ o) {
  const int id = blockIdx.x * 256 + threadIdx.x;  // grid covers exactly 1769472
  if (id < 442368) {                // qkv_w (384,1152) -> [1152][384]
    const int n = id / 384, k = id - n * 384;
    o[id] = f2bf(qkv_w[k * 1152 + n]);
  } else if (id < 589824) {         // proj_w (384,384) -> [384][384]
    const int e = id - 442368; const int n = e / 384, k = e - n * 384;
    o[id] = f2bf(proj_w[k * 384 + n]);
  } else if (id < 1179648) {        // mlp_w1 (384,1536) -> [1536][384]
    const int e = id - 589824; const int n = e / 384, k = e - n * 384;
    o[id] = f2bf(mlp_w1[k * 1536 + n]);
  } else {                          // mlp_w2 (1536,384) -> [384][1536]
    const int e = id - 1179648; const int n = e / 1536, k = e - n * 1536;
    o[id] = f2bf(mlp_w2[k * 384 + n]);
  }
}

// ---------------- continuous relative position bias table -------------------
__global__ __launch_bounds__(256) void biastab_k(
    const float* __restrict__ w1, const float* __restrict__ b1,
    const float* __restrict__ w2, const float* __restrict__ b2,
    float* __restrict__ biasT) {
  const int id = blockIdx.x * 256 + threadIdx.x;
  if (id >= 2401) return;
  const int i = id / 49, j = id - i * 49;
  const int r1 = i / 7, c1 = i - r1 * 7, r2 = j / 7, c2 = j - r2 * 7;
  float dy = (float)(r1 - r2), dx = (float)(c1 - c2);
  dy = copysignf(log1pf(fabsf(dy)), dy);
  dx = copysignf(log1pf(fabsf(dx)), dx);
  float accv[12];
#pragma unroll
  for (int t = 0; t < 12; ++t) accv[t] = b2[t];
  for (int u = 0; u < 64; ++u) {
    float hu = fmaxf(dy * w1[u] + dx * w1[64 + u] + b1[u], 0.0f);
#pragma unroll
    for (int t = 0; t < 12; ++t) accv[t] += hu * w2[u * 12 + t];
  }
#pragma unroll
  for (int t = 0; t < 12; ++t) biasT[t * 2401 + id] = accv[t];
}

// ---------------- LayerNorm (one wave per token), optional shift+window map --
template <int WINMAP>
__global__ __launch_bounds__(256, 4) void ln_k(
    const float* __restrict__ X, const float* __restrict__ g,
    const float* __restrict__ b, u16* __restrict__ O) {
  const int t = blockIdx.x * 4 + (threadIdx.x >> 6);
  const int lane = threadIdx.x & 63;
  const float* xr = X + (size_t)t * 384;
  float v[6];
  float s = 0.f;
#pragma unroll
  for (int i = 0; i < 6; ++i) { v[i] = xr[lane + i * 64]; s += v[i]; }
#pragma unroll
  for (int m = 1; m < 64; m <<= 1) s += __shfl_xor(s, m);
  const float mu = s * (1.0f / 384.0f);
  float q = 0.f;
#pragma unroll
  for (int i = 0; i < 6; ++i) { float d = v[i] - mu; q += d * d; }
#pragma unroll
  for (int m = 1; m < 64; m <<= 1) q += __shfl_xor(q, m);
  const float rstd = rsqrtf(q * (1.0f / 384.0f) + 1e-5f);
  size_t row;
  if constexpr (WINMAP) {
    const int bb = t / 3136, hw = t - bb * 3136;
    const int ho = hw / 56, wo = hw - ho * 56;
    int hs = ho - 3; if (hs < 0) hs += 56;
    int ws2 = wo - 3; if (ws2 < 0) ws2 += 56;
    const int h7 = hs / 7, w7 = ws2 / 7;
    const int wwin = bb * 64 + h7 * 8 + w7;
    const int p = (hs - h7 * 7) * 7 + (ws2 - w7 * 7);
    row = (size_t)wwin * 49 + p;
  } else {
    row = (size_t)t;
  }
  u16* orow = O + row * 384;
#pragma unroll
  for (int i = 0; i < 6; ++i) {
    const int d = lane + i * 64;
    orow[d] = f2bf((v[i] - mu) * rstd * g[d] + b[d]);
  }
}

// ---------------- 64x64-per-wave barrier-free pipelined GEMM -----------------
// One wave per block. A [M][K] bf16 row-major, Bt [N][K] bf16 row-major.
// LDS: wave-private double buffer; stage via gll16 with inverse-swizzled
// global source; ds_read with XOR swizzle  off ^= (row&7)<<3 (u16 units).
// Pipeline: tiles t, t+1 in flight; vmcnt(8) per iter (8 gll16/tile).
// EPI 0: qkv (bias, q/k head L2-norm, tau)   -> bf16
// EPI 1: proj (bias + residual + win-reverse)-> f32 d_out
// EPI 2: mlp1 (bias + exact gelu)            -> bf16
// EPI 3: mlp2 (bias, accumulate)             -> f32 +=
template <int EPI>
__global__ __launch_bounds__(64, 2) void gemm_k(
    const u16* __restrict__ A, const u16* __restrict__ Bt,
    const float* __restrict__ bias, const float* __restrict__ aux,
    void* __restrict__ outp, int M, int N, int K) {
  __shared__ u16 Abuf[2][2048];
  __shared__ u16 Bbuf[2][2048];
  const int lane = threadIdx.x;
  const int l15 = lane & 15, l4 = lane >> 4;

  // XCD-chunked swizzle (all grids have nwg % 8 == 0)
  const int nx = gridDim.x;
  const int nwg = nx * gridDim.y;
  int bid = blockIdx.y * nx + blockIdx.x;
  bid = (bid & 7) * (nwg >> 3) + (bid >> 3);
  const int tileN = (bid % nx) * 64;
  const int tileM = (bid / nx) * 64;

  // --- staging source with T2-inverse swizzle (rule #21) ---
  // physical: chunk c, row prow = c*16 + (lane>>2), slot pslot = lane&3.
  // logical source: Lrow flips bit0 by bit2; Lslot ^= (Lrow&3).
  const int prow_l = lane >> 2;
  const int lrow_l = prow_l ^ ((prow_l >> 2) & 1);
  const int lslot = (lane & 3) ^ (lrow_l & 3);
  const u16* Ag = A + (size_t)(tileM + lrow_l) * K + lslot * 8;
  const u16* Bg = Bt + (size_t)(tileN + lrow_l) * K + lslot * 8;
  const size_t cstrideA = (size_t)16 * K;

  f32x4 acc[4][4] = {};

#define STAGE(k0, b)                                             \
  {                                                              \
    _Pragma("unroll") for (int c = 0; c < 4; ++c) {              \
      gll16(Ag + (size_t)c * cstrideA + (k0), &Abuf[b][c * 512]);\
      gll16(Bg + (size_t)c * cstrideA + (k0), &Bbuf[b][c * 512]);\
    }                                                            \
  }

#define COMPUTE(b)                                                        \
  {                                                                       \
    bf16x8 af[4], bfr[4];                                                 \
    _Pragma("unroll") for (int f = 0; f < 4; ++f) {                       \
      const int R = f * 16 + l15;                                         \
      const int off = (R * 32 + 8 * l4) ^ ((R & 7) << 3);                 \
      af[f] = *(const bf16x8*)&Abuf[b][off];                              \
      bfr[f] = *(const bf16x8*)&Bbuf[b][off];                             \
    }                                                                     \
    __builtin_amdgcn_s_setprio(1);                                        \
    _Pragma("unroll") for (int fm = 0; fm < 4; ++fm)                      \
        _Pragma("unroll") for (int fn = 0; fn < 4; ++fn) acc[fm][fn] =    \
            __builtin_amdgcn_mfma_f32_16x16x32_bf16(af[fm], bfr[fn],      \
                                                    acc[fm][fn], 0, 0, 0);\
    __builtin_amdgcn_s_setprio(0);                                        \
  }

  const int nt = K >> 5;
  STAGE(0, 0);
  STAGE(32, 1);
  for (int t = 0; t + 2 < nt; ++t) {
    VMW8;                       // tile t's 8 loads retired; t+1's in flight
    COMPUTE(t & 1);
    LGKM0;                      // ds_reads of buf done before overwrite
    STAGE((size_t)(t + 2) * 32, t & 1);
  }
  VMW8;
  COMPUTE(nt & 1);              // t = nt-2
  VMW0;
  COMPUTE((nt - 1) & 1);        // t = nt-1
#undef STAGE
#undef COMPUTE

  if constexpr (EPI == 0) {
    u16* O = (u16*)outp;
#pragma unroll
    for (int fm = 0; fm < 4; ++fm) {
#pragma unroll
      for (int hp = 0; hp < 2; ++hp) {
        const int c0e = tileN + hp * 32;
        const int seg = c0e >> 5;            // 0..11 q, 12..23 k, 24..35 v
        const bool nrm = seg < 24;
        const float tfac = (seg < 12) ? aux[seg] : 1.0f;
        const float b0 = bias[c0e + l15];
        const float b1 = bias[c0e + 16 + l15];
#pragma unroll
        for (int r = 0; r < 4; ++r) {
          float v0 = acc[fm][2 * hp][r] + b0;
          float v1 = acc[fm][2 * hp + 1][r] + b1;
          if (nrm) {
            float ss = v0 * v0 + v1 * v1;
            ss += __shfl_xor(ss, 1);
            ss += __shfl_xor(ss, 2);
            ss += __shfl_xor(ss, 4);
            ss += __shfl_xor(ss, 8);
            const float f = tfac / fmaxf(sqrtf(ss), 1e-12f);
            v0 *= f; v1 *= f;
          }
          const size_t row = (size_t)(tileM + fm * 16 + l4 * 4 + r);
          O[row * N + c0e + l15] = f2bf(v0);
          O[row * N + c0e + 16 + l15] = f2bf(v1);
        }
      }
    }
  } else if constexpr (EPI == 1) {
    float* O = (float*)outp;
    const float* X = aux;
#pragma unroll
    for (int fm = 0; fm < 4; ++fm) {
#pragma unroll
      for (int r = 0; r < 4; ++r) {
        const int row = tileM + fm * 16 + l4 * 4 + r;
        const int w = row / 49, p = row - w * 49;
        const int bb = w >> 6, widx = w & 63;
        const int p7 = p / 7;
        int hs = (widx >> 3) * 7 + p7;
        int ws2 = (widx & 7) * 7 + (p - p7 * 7);
        int ho = hs + 3; if (ho >= 56) ho -= 56;
        int wo = ws2 + 3; if (wo >= 56) wo -= 56;
        const size_t tok = (size_t)bb * 3136 + ho * 56 + wo;
#pragma unroll
        for (int fn = 0; fn < 4; ++fn) {
          const int col = tileN + fn * 16 + l15;
          O[tok * 384 + col] = X[tok * 384 + col] + acc[fm][fn][r] + bias[col];
        }
      }
    }
  } else if constexpr (EPI == 2) {
    u16* O = (u16*)outp;
#pragma unroll
    for (int fm = 0; fm < 4; ++fm) {
#pragma unroll
      for (int fn = 0; fn < 4; ++fn) {
        const int col = tileN + fn * 16 + l15;
        const float bc = bias[col];
#pragma unroll
        for (int r = 0; r < 4; ++r) {
          const size_t row = (size_t)(tileM + fm * 16 + l4 * 4 + r);
          const float v = acc[fm][fn][r] + bc;
          const float g = 0.5f * v * (1.0f + erff(v * 0.70710678118654752f));
          O[row * N + col] = f2bf(g);
        }
      }
    }
  } else {
    float* O = (float*)outp;
#pragma unroll
    for (int fm = 0; fm < 4; ++fm) {
#pragma unroll
      for (int fn = 0; fn < 4; ++fn) {
        const int col = tileN + fn * 16 + l15;
        const float bc = bias[col];
#pragma unroll
        for (int r = 0; r < 4; ++r) {
          const size_t row = (size_t)(tileM + fm * 16 + l4 * 4 + r);
          O[row * N + col] += acc[fm][fn][r] + bc;
        }
      }
    }
  }
}

// ---------------- attention: one wave per (window, head), barrier-free -------
__global__ __launch_bounds__(256, 2) void attn_k(
    const u16* __restrict__ qkv, const float* __restrict__ biasT,
    u16* __restrict__ outp) {
  __shared__ u16 lds[4][7552];
  const int tid = threadIdx.x, lane = tid & 63, wid = tid >> 6;
  const int l15 = lane & 15, l4 = lane >> 4;
  const int W = blockIdx.x * 4 + wid;
  const int w = W / 12, h = W - w * 12;
  u16* S = lds[wid];
  u16* Q = S;
  u16* Kl = S + 2560;
  u16* P = S;
  u16* VT = S + 5120;
  float* sums = (float*)(S + 7424);
  const u16* base = qkv + (size_t)w * 56448 + h * 32;  // 49*1152
  const int widx = w & 63, wh = widx >> 3, ww = widx & 7;
  const bool masked = (wh == 7) || (ww == 7);

#pragma unroll
  for (int it = 0; it < 4; ++it) {
    const int row = it * 16 + (lane >> 2);
    const int c8 = (lane & 3) * 8;
    uint4 qv = {0, 0, 0, 0}, kv = {0, 0, 0, 0};
    if (row < 49) {
      qv = *(const uint4*)(base + (size_t)row * 1152 + c8);
      kv = *(const uint4*)(base + (size_t)row * 1152 + 384 + c8);
    }
    *(uint4*)&Q[row * 40 + c8] = qv;
    *(uint4*)&Kl[row * 40 + c8] = kv;
  }
  {
    const int d = lane & 31;
    const int jh = lane >> 5;
#pragma unroll 4
    for (int jt = 0; jt < 32; ++jt) {
      const int j = jt * 2 + jh;
      u16 val = 0;
      if (j < 49) val = base[(size_t)j * 1152 + 768 + d];
      VT[d * 72 + j] = val;
    }
  }
  LGKM0;  // wave-private LDS: writes visible to own reads

  f32x4 sc[4][4] = {};
  {
    bf16x8 aq[4], bk[4];
#pragma unroll
    for (int f = 0; f < 4; ++f)
      aq[f] = *(const bf16x8*)&Q[(f * 16 + l15) * 40 + 8 * l4];
#pragma unroll
    for (int f = 0; f < 4; ++f)
      bk[f] = *(const bf16x8*)&Kl[(f * 16 + l15) * 40 + 8 * l4];
    __builtin_amdgcn_s_setprio(1);
#pragma unroll
    for (int fm = 0; fm < 4; ++fm)
#pragma unroll
      for (int fn = 0; fn < 4; ++fn)
        sc[fm][fn] = __builtin_amdgcn_mfma_f32_16x16x32_bf16(
            aq[fm], bk[fn], sc[fm][fn], 0, 0, 0);
    __builtin_amdgcn_s_setprio(0);
  }
  LGKM0;  // Q/K fragment reads complete before P overlays them

  int codej[4] = {0, 0, 0, 0};
  if (masked) {
#pragma unroll
    for (int fn = 0; fn < 4; ++fn) {
      const int j = fn * 16 + l15;
      const int pr = j / 7, pc = j - pr * 7;
      const int rr2 = (wh == 7) ? ((pr < 4) ? 1 : 2) : 0;
      const int cc2 = (ww == 7) ? ((pc < 4) ? 1 : 2) : 0;
      codej[fn] = rr2 * 3 + cc2;
    }
  }
#pragma unroll
  for (int fm = 0; fm < 4; ++fm) {
#pragma unroll
    for (int r = 0; r < 4; ++r) {
      const int i = fm * 16 + l4 * 4 + r;
      const bool iok = i < 49;
      int ci = 0;
      if (masked && iok) {
        const int pr = i / 7, pc = i - pr * 7;
        const int rr2 = (wh == 7) ? ((pr < 4) ? 1 : 2) : 0;
        const int cc2 = (ww == 7) ? ((pc < 4) ? 1 : 2) : 0;
        ci = rr2 * 3 + cc2;
      }
      const float* brow = biasT + (size_t)h * 2401 + (iok ? i : 0) * 49;
      float sv[4];
#pragma unroll
      for (int fn = 0; fn < 4; ++fn) {
        const int j = fn * 16 + l15;
        float s = sc[fm][fn][r];
        if (iok && j < 49) {
          s += brow[j];
          if (masked && codej[fn] != ci) s -= 100.0f;
        } else {
          s = -1e30f;
        }
        sv[fn] = s;
      }
      float mx = fmaxf(fmaxf(sv[0], sv[1]), fmaxf(sv[2], sv[3]));
      mx = fmaxf(mx, __shfl_xor(mx, 1));
      mx = fmaxf(mx, __shfl_xor(mx, 2));
      mx = fmaxf(mx, __shfl_xor(mx, 4));
      mx = fmaxf(mx, __shfl_xor(mx, 8));
      float sm = 0.f;
      u16 pb[4];
#pragma unroll
      for (int fn = 0; fn < 4; ++fn) {
        const float e = __expf(sv[fn] - mx);
        sm += e;
        pb[fn] = f2bf(e);
      }
      sm += __shfl_xor(sm, 1);
      sm += __shfl_xor(sm, 2);
      sm += __shfl_xor(sm, 4);
      sm += __shfl_xor(sm, 8);
#pragma unroll
      for (int fn = 0; fn < 4; ++fn) P[i * 72 + fn * 16 + l15] = pb[fn];
      if (l15 == 0) sums[i] = sm;
    }
  }
  LGKM0;  // P/sums writes visible

  f32x4 o[4][2] = {};
#pragma unroll
  for (int kk = 0; kk < 2; ++kk) {
    bf16x8 pa[4], bv[2];
#pragma unroll
    for (int fm = 0; fm < 4; ++fm)
      pa[fm] = *(const bf16x8*)&P[(fm * 16 + l15) * 72 + kk * 32 + 8 * l4];
#pragma unroll
    for (int fn = 0; fn < 2; ++fn)
      bv[fn] = *(const bf16x8*)&VT[(fn * 16 + l15) * 72 + kk * 32 + 8 * l4];
    __builtin_amdgcn_s_setprio(1);
#pragma unroll
    for (int fm = 0; fm < 4; ++fm)
#pragma unroll
      for (int fn = 0; fn < 2; ++fn)
        o[fm][fn] = __builtin_amdgcn_mfma_f32_16x16x32_bf16(
            pa[fm], bv[fn], o[fm][fn], 0, 0, 0);
    __builtin_amdgcn_s_setprio(0);
  }
  u16* ob = outp + (size_t)w * 49 * 384 + h * 32;
#pragma unroll
  for (int fm = 0; fm < 4; ++fm) {
#pragma unroll
    for (int r = 0; r < 4; ++r) {
      const int i = fm * 16 + l4 * 4 + r;
      if (i < 49) {
        const float inv = 1.0f / sums[i];
        ob[(size_t)i * 384 + l15] = f2bf(o[fm][0][r] * inv);
        ob[(size_t)i * 384 + 16 + l15] = f2bf(o[fm][1][r] * inv);
      }
    }
  }
}

// ---------------------------------------------------------------------------
extern "C" void kernel_launch(void* const* d_in, const int* in_sizes, int n_in,
                              void* d_out, int out_size, void* d_ws,
                              size_t ws_size, hipStream_t stream) {
  const float* x      = (const float*)d_in[0];
  const float* n1g    = (const float*)d_in[1];
  const float* n1b    = (const float*)d_in[2];
  const float* qkv_w  = (const float*)d_in[3];
  const float* qkv_b  = (const float*)d_in[4];
  const float* tau    = (const float*)d_in[5];
  const float* proj_w = (const float*)d_in[6];
  const float* proj_b = (const float*)d_in[7];
  const float* c_w1   = (const float*)d_in[8];
  const float* c_b1   = (const float*)d_in[9];
  const float* c_w2   = (const float*)d_in[10];
  const float* c_b2   = (const float*)d_in[11];
  const float* n2g    = (const float*)d_in[12];
  const float* n2b    = (const float*)d_in[13];
  const float* mlp_w1 = (const float*)d_in[14];
  const float* mlp_b1 = (const float*)d_in[15];
  const float* mlp_w2 = (const float*)d_in[16];
  const float* mlp_b2 = (const float*)d_in[17];
  float* out = (float*)d_out;
  char* ws = (char*)d_ws;

  // ws layout (bytes)
  constexpr size_t WS_WT    = 0;          // bf16 weights^T, 3538944 B
  constexpr size_t WS_BIAST = 3538944;    // f32 [12][49][49]
  constexpr size_t WS_XW    = 4194304;    // bf16 [100352][384]  (also ln2)
  constexpr size_t WS_QKV   = 81264640;   // bf16 [100352][1152] (also hidden lo)
  constexpr size_t WS_ATT   = 312475648;  // bf16 [100352][384]  (also hidden hi)
  constexpr size_t WS_NEED  = 389545984;

  if (ws_size < WS_NEED) {  // distinctive sentinel: absmax ~12345 => ws too small
    fill_k<<<(out_size + 255) / 256, 256, 0, stream>>>(out, out_size);
    return;
  }

  u16* wqkvT  = (u16*)(ws + WS_WT);
  u16* wprojT = (u16*)(ws + WS_WT + 884736);
  u16* wm1T   = (u16*)(ws + WS_WT + 1179648);
  u16* wm2T   = (u16*)(ws + WS_WT + 2359296);
  float* biasT = (float*)(ws + WS_BIAST);
  u16* xw  = (u16*)(ws + WS_XW);
  u16* qkv = (u16*)(ws + WS_QKV);
  u16* att = (u16*)(ws + WS_ATT);
  u16* hid = qkv;   // [100352][1536] spans qkv+att regions exactly
  u16* ln2 = xw;

  wconv_k<<<6912, 256, 0, stream>>>(qkv_w, proj_w, mlp_w1, mlp_w2, (u16*)ws);
  biastab_k<<<10, 256, 0, stream>>>(c_w1, c_b1, c_w2, c_b2, biasT);
  ln_k<1><<<25088, 256, 0, stream>>>(x, n1g, n1b, xw);
  gemm_k<0><<<dim3(18, 1568), 64, 0, stream>>>(xw, wqkvT, qkv_b, tau, qkv,
                                               100352, 1152, 384);
  attn_k<<<6144, 256, 0, stream>>>(qkv, biasT, att);
  gemm_k<1><<<dim3(6, 1568), 64, 0, stream>>>(att, wprojT, proj_b, x, out,
                                              100352, 384, 384);
  ln_k<0><<<25088, 256, 0, stream>>>(out, n2g, n2b, ln2);
  gemm_k<2><<<dim3(24, 1568), 64, 0, stream>>>(ln2, wm1T, mlp_b1, nullptr, hid,
                                               100352, 1536, 384);
  gemm_k<3><<<dim3(6, 1568), 64, 0, stream>>>(hid, wm2T, mlp_b2, nullptr, out,
                                              100352, 384, 1536);
}

// Round 4
// 1426.721 us; speedup vs baseline: 1.2119x; 1.2119x over previous
//
#include <hip/hip_runtime.h>
#include <cstdint>
#include <cstddef>

// ---------------------------------------------------------------------------
// SwinV2 block, MI355X bf16-MFMA implementation.
// Round 4: 128x128 GEMM, 256 thr, triple-buffered LDS, depth-2 prefetch,
// counted vmcnt(8) + raw s_barrier (no __syncthreads drain), T2 swizzle,
// setprio around MFMA. Attn barrier-free (wave-private LDS + lgkmcnt).
// ---------------------------------------------------------------------------

typedef unsigned short u16;
typedef __bf16 bf16x8 __attribute__((ext_vector_type(8)));
typedef float f32x4 __attribute__((ext_vector_type(4)));

#define VMW8 asm volatile("s_waitcnt vmcnt(8)" ::: "memory")
#define VMW4 asm volatile("s_waitcnt vmcnt(4)" ::: "memory")
#define VMW0 asm volatile("s_waitcnt vmcnt(0)" ::: "memory")
#define LGKM0 asm volatile("s_waitcnt lgkmcnt(0)" ::: "memory")
#define BAR asm volatile("s_barrier" ::: "memory")

__device__ __forceinline__ u16 f2bf(float f) {
  unsigned u = __builtin_bit_cast(unsigned, f);
  u += 0x7fffu + ((u >> 16) & 1u);
  return (u16)(u >> 16);
}

// async global->LDS, 16 bytes per lane; lane i's 16B land at base + i*16.
__device__ __forceinline__ void gll16(const u16* g, u16* l) {
  __builtin_amdgcn_global_load_lds(
      (const __attribute__((address_space(1))) void*)g,
      (__attribute__((address_space(3))) void*)l, 16, 0, 0);
}

// ---------------- diagnostics: ws too small sentinel ----------------
__global__ __launch_bounds__(256) void fill_k(float* o, int n) {
  int i = blockIdx.x * 256 + threadIdx.x;
  if (i < n) o[i] = 12345.0f;
}

// ---------------- weight convert + transpose (fp32 [K][N] -> bf16 [N][K]) ----
__global__ __launch_bounds__(256) void wconv_k(
    const float* __restrict__ qkv_w, const float* __restrict__ proj_w,
    const float* __restrict__ mlp_w1, const float* __restrict__ mlp_w2,
    u16* __restrict__ o) {
  const int id = blockIdx.x * 256 + threadIdx.x;  // grid covers exactly 1769472
  if (id < 442368) {                // qkv_w (384,1152) -> [1152][384]
    const int n = id / 384, k = id - n * 384;
    o[id] = f2bf(qkv_w[k * 1152 + n]);
  } else if (id < 589824) {         // proj_w (384,384) -> [384][384]
    const int e = id - 442368; const int n = e / 384, k = e - n * 384;
    o[id] = f2bf(proj_w[k * 384 + n]);
  } else if (id < 1179648) {        // mlp_w1 (384,1536) -> [1536][384]
    const int e = id - 589824; const int n = e / 384, k = e - n * 384;
    o[id] = f2bf(mlp_w1[k * 1536 + n]);
  } else {                          // mlp_w2 (1536,384) -> [384][1536]
    const int e = id - 1179648; const int n = e / 1536, k = e - n * 1536;
    o[id] = f2bf(mlp_w2[k * 384 + n]);
  }
}

// ---------------- continuous relative position bias table -------------------
__global__ __launch_bounds__(256) void biastab_k(
    const float* __restrict__ w1, const float* __restrict__ b1,
    const float* __restrict__ w2, const float* __restrict__ b2,
    float* __restrict__ biasT) {
  const int id = blockIdx.x * 256 + threadIdx.x;
  if (id >= 2401) return;
  const int i = id / 49, j = id - i * 49;
  const int r1 = i / 7, c1 = i - r1 * 7, r2 = j / 7, c2 = j - r2 * 7;
  float dy = (float)(r1 - r2), dx = (float)(c1 - c2);
  dy = copysignf(log1pf(fabsf(dy)), dy);
  dx = copysignf(log1pf(fabsf(dx)), dx);
  float accv[12];
#pragma unroll
  for (int t = 0; t < 12; ++t) accv[t] = b2[t];
  for (int u = 0; u < 64; ++u) {
    float hu = fmaxf(dy * w1[u] + dx * w1[64 + u] + b1[u], 0.0f);
#pragma unroll
    for (int t = 0; t < 12; ++t) accv[t] += hu * w2[u * 12 + t];
  }
#pragma unroll
  for (int t = 0; t < 12; ++t) biasT[t * 2401 + id] = accv[t];
}

// ---------------- LayerNorm (one wave per token), optional shift+window map --
template <int WINMAP>
__global__ __launch_bounds__(256, 4) void ln_k(
    const float* __restrict__ X, const float* __restrict__ g,
    const float* __restrict__ b, u16* __restrict__ O) {
  const int t = blockIdx.x * 4 + (threadIdx.x >> 6);
  const int lane = threadIdx.x & 63;
  const float* xr = X + (size_t)t * 384;
  float v[6];
  float s = 0.f;
#pragma unroll
  for (int i = 0; i < 6; ++i) { v[i] = xr[lane + i * 64]; s += v[i]; }
#pragma unroll
  for (int m = 1; m < 64; m <<= 1) s += __shfl_xor(s, m);
  const float mu = s * (1.0f / 384.0f);
  float q = 0.f;
#pragma unroll
  for (int i = 0; i < 6; ++i) { float d = v[i] - mu; q += d * d; }
#pragma unroll
  for (int m = 1; m < 64; m <<= 1) q += __shfl_xor(q, m);
  const float rstd = rsqrtf(q * (1.0f / 384.0f) + 1e-5f);
  size_t row;
  if constexpr (WINMAP) {
    const int bb = t / 3136, hw = t - bb * 3136;
    const int ho = hw / 56, wo = hw - ho * 56;
    int hs = ho - 3; if (hs < 0) hs += 56;
    int ws2 = wo - 3; if (ws2 < 0) ws2 += 56;
    const int h7 = hs / 7, w7 = ws2 / 7;
    const int wwin = bb * 64 + h7 * 8 + w7;
    const int p = (hs - h7 * 7) * 7 + (ws2 - w7 * 7);
    row = (size_t)wwin * 49 + p;
  } else {
    row = (size_t)t;
  }
  u16* orow = O + row * 384;
#pragma unroll
  for (int i = 0; i < 6; ++i) {
    const int d = lane + i * 64;
    orow[d] = f2bf((v[i] - mu) * rstd * g[d] + b[d]);
  }
}

// ---------------- 128x128 pipelined GEMM (triple-buffer, counted vmcnt) ------
// A [M][KK] bf16 row-major, Bt [N][KK] bf16 row-major (W transposed).
// EPI 0: qkv (bias, q/k head L2-norm, tau)   -> bf16
// EPI 1: proj (bias + residual + win-reverse)-> f32 d_out
// EPI 2: mlp1 (bias + exact gelu)            -> bf16
// EPI 3: mlp2 (bias, accumulate)             -> f32 +=
template <int EPI, int KK>
__global__ __launch_bounds__(256, 3) void gemm_k(
    const u16* __restrict__ A, const u16* __restrict__ Bt,
    const float* __restrict__ bias, const float* __restrict__ aux,
    void* __restrict__ outp, int M, int N) {
  __shared__ u16 Ab[3][4096];
  __shared__ u16 Bb[3][4096];
  const int tid = threadIdx.x;
  const int lane = tid & 63;
  const int wv = tid >> 6;
  const int wrow = wv >> 1, wcol = wv & 1;
  const int l15 = lane & 15, l4 = lane >> 4;

  // XCD-chunked swizzle (all grids have nwg % 8 == 0)
  const int nx = gridDim.x;
  const int nwg = nx * gridDim.y;
  int bid = blockIdx.y * nx + blockIdx.x;
  bid = (bid & 7) * (nwg >> 3) + (bid >> 3);
  const int tileN = (bid % nx) * 128;
  const int tileM = (bid / nx) * 128;

  // --- staging source with T2-inverse swizzle (rule #21, verified round 3) ---
  // physical within 16-row chunk: prow = lane>>2, pslot = lane&3.
  const int prow = lane >> 2;
  const int lrow = prow ^ ((prow >> 2) & 1);
  const int lslot = (lane & 3) ^ (lrow & 3);
  const u16* Ag = A + (size_t)(tileM + wv * 16 + lrow) * KK + lslot * 8;
  const u16* Bg = Bt + (size_t)(tileN + wv * 16 + lrow) * KK + lslot * 8;
  const size_t skip = (size_t)64 * KK;

  f32x4 acc[4][4] = {};

#define STAGE(t, b)                                       \
  {                                                       \
    const size_t ko = (size_t)(t) * 32;                   \
    gll16(Ag + ko, &Ab[b][wv * 512]);                     \
    gll16(Ag + skip + ko, &Ab[b][(4 + wv) * 512]);        \
    gll16(Bg + ko, &Bb[b][wv * 512]);                     \
    gll16(Bg + skip + ko, &Bb[b][(4 + wv) * 512]);        \
  }

#define COMPUTE(b)                                                        \
  {                                                                       \
    bf16x8 af[4], bfr[4];                                                 \
    _Pragma("unroll") for (int f = 0; f < 4; ++f) {                       \
      const int Ra = wrow * 64 + f * 16 + l15;                            \
      const int Rb = wcol * 64 + f * 16 + l15;                            \
      af[f] = *(const bf16x8*)&Ab[b][(Ra * 32 + 8 * l4) ^ ((Ra & 7) << 3)];\
      bfr[f] = *(const bf16x8*)&Bb[b][(Rb * 32 + 8 * l4) ^ ((Rb & 7) << 3)];\
    }                                                                     \
    __builtin_amdgcn_s_setprio(1);                                        \
    _Pragma("unroll") for (int fm = 0; fm < 4; ++fm)                      \
        _Pragma("unroll") for (int fn = 0; fn < 4; ++fn) acc[fm][fn] =    \
            __builtin_amdgcn_mfma_f32_16x16x32_bf16(af[fm], bfr[fn],      \
                                                    acc[fm][fn], 0, 0, 0);\
    __builtin_amdgcn_s_setprio(0);                                        \
  }

  constexpr int nt = KK >> 5;  // 12 or 48
  STAGE(0, 0);
  STAGE(1, 1);
  int cur = 0, nxt = 2;
#pragma unroll 3
  for (int t = 0; t < nt - 2; ++t) {
    STAGE(t + 2, nxt);
    VMW8;              // own tile-t loads retired (t+1,t+2 stay in flight)
    BAR;               // all waves' tile-t chunks visible
    COMPUTE(cur);
    BAR;               // all reads done before next iter overwrites buf cur
    cur = (cur == 2) ? 0 : cur + 1;
    nxt = (nxt == 2) ? 0 : nxt + 1;
  }
  VMW4;
  BAR;
  COMPUTE(cur);        // tile nt-2
  cur = (cur == 2) ? 0 : cur + 1;
  VMW0;
  BAR;
  COMPUTE(cur);        // tile nt-1
#undef STAGE
#undef COMPUTE

  const int baseRow = tileM + wrow * 64;
  const int baseCol = tileN + wcol * 64;

  if constexpr (EPI == 0) {
    u16* O = (u16*)outp;
#pragma unroll
    for (int fm = 0; fm < 4; ++fm) {
#pragma unroll
      for (int hp = 0; hp < 2; ++hp) {
        const int c0e = baseCol + hp * 32;
        const int seg = c0e >> 5;            // 0..11 q, 12..23 k, 24..35 v
        const bool nrm = seg < 24;
        const float tfac = (seg < 12) ? aux[seg] : 1.0f;
        const float b0 = bias[c0e + l15];
        const float b1 = bias[c0e + 16 + l15];
#pragma unroll
        for (int r = 0; r < 4; ++r) {
          float v0 = acc[fm][2 * hp][r] + b0;
          float v1 = acc[fm][2 * hp + 1][r] + b1;
          if (nrm) {
            float ss = v0 * v0 + v1 * v1;
            ss += __shfl_xor(ss, 1);
            ss += __shfl_xor(ss, 2);
            ss += __shfl_xor(ss, 4);
            ss += __shfl_xor(ss, 8);
            const float f = tfac / fmaxf(sqrtf(ss), 1e-12f);
            v0 *= f; v1 *= f;
          }
          const size_t row = (size_t)(baseRow + fm * 16 + l4 * 4 + r);
          O[row * N + c0e + l15] = f2bf(v0);
          O[row * N + c0e + 16 + l15] = f2bf(v1);
        }
      }
    }
  } else if constexpr (EPI == 1) {
    float* O = (float*)outp;
    const float* X = aux;
#pragma unroll
    for (int fm = 0; fm < 4; ++fm) {
#pragma unroll
      for (int r = 0; r < 4; ++r) {
        const int row = baseRow + fm * 16 + l4 * 4 + r;
        const int w = row / 49, p = row - w * 49;
        const int bb = w >> 6, widx = w & 63;
        const int p7 = p / 7;
        int hs = (widx >> 3) * 7 + p7;
        int ws2 = (widx & 7) * 7 + (p - p7 * 7);
        int ho = hs + 3; if (ho >= 56) ho -= 56;
        int wo = ws2 + 3; if (wo >= 56) wo -= 56;
        const size_t tok = (size_t)bb * 3136 + ho * 56 + wo;
#pragma unroll
        for (int fn = 0; fn < 4; ++fn) {
          const int col = baseCol + fn * 16 + l15;
          O[tok * 384 + col] = X[tok * 384 + col] + acc[fm][fn][r] + bias[col];
        }
      }
    }
  } else if constexpr (EPI == 2) {
    u16* O = (u16*)outp;
#pragma unroll
    for (int fm = 0; fm < 4; ++fm) {
#pragma unroll
      for (int fn = 0; fn < 4; ++fn) {
        const int col = baseCol + fn * 16 + l15;
        const float bc = bias[col];
#pragma unroll
        for (int r = 0; r < 4; ++r) {
          const size_t row = (size_t)(baseRow + fm * 16 + l4 * 4 + r);
          const float v = acc[fm][fn][r] + bc;
          const float g = 0.5f * v * (1.0f + erff(v * 0.70710678118654752f));
          O[row * N + col] = f2bf(g);
        }
      }
    }
  } else {
    float* O = (float*)outp;
#pragma unroll
    for (int fm = 0; fm < 4; ++fm) {
#pragma unroll
      for (int fn = 0; fn < 4; ++fn) {
        const int col = baseCol + fn * 16 + l15;
        const float bc = bias[col];
#pragma unroll
        for (int r = 0; r < 4; ++r) {
          const size_t row = (size_t)(baseRow + fm * 16 + l4 * 4 + r);
          O[row * N + col] += acc[fm][fn][r] + bc;
        }
      }
    }
  }
}

// ---------------- attention: one wave per (window, head), barrier-free -------
__global__ __launch_bounds__(256, 2) void attn_k(
    const u16* __restrict__ qkv, const float* __restrict__ biasT,
    u16* __restrict__ outp) {
  __shared__ u16 lds[4][7552];
  const int tid = threadIdx.x, lane = tid & 63, wid = tid >> 6;
  const int l15 = lane & 15, l4 = lane >> 4;
  const int W = blockIdx.x * 4 + wid;
  const int w = W / 12, h = W - w * 12;
  u16* S = lds[wid];
  u16* Q = S;
  u16* Kl = S + 2560;
  u16* P = S;
  u16* VT = S + 5120;
  float* sums = (float*)(S + 7424);
  const u16* base = qkv + (size_t)w * 56448 + h * 32;  // 49*1152
  const int widx = w & 63, wh = widx >> 3, ww = widx & 7;
  const bool masked = (wh == 7) || (ww == 7);

#pragma unroll
  for (int it = 0; it < 4; ++it) {
    const int row = it * 16 + (lane >> 2);
    const int c8 = (lane & 3) * 8;
    uint4 qv = {0, 0, 0, 0}, kv = {0, 0, 0, 0};
    if (row < 49) {
      qv = *(const uint4*)(base + (size_t)row * 1152 + c8);
      kv = *(const uint4*)(base + (size_t)row * 1152 + 384 + c8);
    }
    *(uint4*)&Q[row * 40 + c8] = qv;
    *(uint4*)&Kl[row * 40 + c8] = kv;
  }
  {
    const int d = lane & 31;
    const int jh = lane >> 5;
#pragma unroll 4
    for (int jt = 0; jt < 32; ++jt) {
      const int j = jt * 2 + jh;
      u16 val = 0;
      if (j < 49) val = base[(size_t)j * 1152 + 768 + d];
      VT[d * 72 + j] = val;
    }
  }
  LGKM0;  // wave-private LDS: writes visible to own reads

  f32x4 sc[4][4] = {};
  {
    bf16x8 aq[4], bk[4];
#pragma unroll
    for (int f = 0; f < 4; ++f)
      aq[f] = *(const bf16x8*)&Q[(f * 16 + l15) * 40 + 8 * l4];
#pragma unroll
    for (int f = 0; f < 4; ++f)
      bk[f] = *(const bf16x8*)&Kl[(f * 16 + l15) * 40 + 8 * l4];
    __builtin_amdgcn_s_setprio(1);
#pragma unroll
    for (int fm = 0; fm < 4; ++fm)
#pragma unroll
      for (int fn = 0; fn < 4; ++fn)
        sc[fm][fn] = __builtin_amdgcn_mfma_f32_16x16x32_bf16(
            aq[fm], bk[fn], sc[fm][fn], 0, 0, 0);
    __builtin_amdgcn_s_setprio(0);
  }
  LGKM0;  // Q/K fragment reads complete before P overlays them

  int codej[4] = {0, 0, 0, 0};
  if (masked) {
#pragma unroll
    for (int fn = 0; fn < 4; ++fn) {
      const int j = fn * 16 + l15;
      const int pr = j / 7, pc = j - pr * 7;
      const int rr2 = (wh == 7) ? ((pr < 4) ? 1 : 2) : 0;
      const int cc2 = (ww == 7) ? ((pc < 4) ? 1 : 2) : 0;
      codej[fn] = rr2 * 3 + cc2;
    }
  }
#pragma unroll
  for (int fm = 0; fm < 4; ++fm) {
#pragma unroll
    for (int r = 0; r < 4; ++r) {
      const int i = fm * 16 + l4 * 4 + r;
      const bool iok = i < 49;
      int ci = 0;
      if (masked && iok) {
        const int pr = i / 7, pc = i - pr * 7;
        const int rr2 = (wh == 7) ? ((pr < 4) ? 1 : 2) : 0;
        const int cc2 = (ww == 7) ? ((pc < 4) ? 1 : 2) : 0;
        ci = rr2 * 3 + cc2;
      }
      const float* brow = biasT + (size_t)h * 2401 + (iok ? i : 0) * 49;
      float sv[4];
#pragma unroll
      for (int fn = 0; fn < 4; ++fn) {
        const int j = fn * 16 + l15;
        float s = sc[fm][fn][r];
        if (iok && j < 49) {
          s += brow[j];
          if (masked && codej[fn] != ci) s -= 100.0f;
        } else {
          s = -1e30f;
        }
        sv[fn] = s;
      }
      float mx = fmaxf(fmaxf(sv[0], sv[1]), fmaxf(sv[2], sv[3]));
      mx = fmaxf(mx, __shfl_xor(mx, 1));
      mx = fmaxf(mx, __shfl_xor(mx, 2));
      mx = fmaxf(mx, __shfl_xor(mx, 4));
      mx = fmaxf(mx, __shfl_xor(mx, 8));
      float sm = 0.f;
      u16 pb[4];
#pragma unroll
      for (int fn = 0; fn < 4; ++fn) {
        const float e = __expf(sv[fn] - mx);
        sm += e;
        pb[fn] = f2bf(e);
      }
      sm += __shfl_xor(sm, 1);
      sm += __shfl_xor(sm, 2);
      sm += __shfl_xor(sm, 4);
      sm += __shfl_xor(sm, 8);
#pragma unroll
      for (int fn = 0; fn < 4; ++fn) P[i * 72 + fn * 16 + l15] = pb[fn];
      if (l15 == 0) sums[i] = sm;
    }
  }
  LGKM0;  // P/sums writes visible

  f32x4 o[4][2] = {};
#pragma unroll
  for (int kk = 0; kk < 2; ++kk) {
    bf16x8 pa[4], bv[2];
#pragma unroll
    for (int fm = 0; fm < 4; ++fm)
      pa[fm] = *(const bf16x8*)&P[(fm * 16 + l15) * 72 + kk * 32 + 8 * l4];
#pragma unroll
    for (int fn = 0; fn < 2; ++fn)
      bv[fn] = *(const bf16x8*)&VT[(fn * 16 + l15) * 72 + kk * 32 + 8 * l4];
    __builtin_amdgcn_s_setprio(1);
#pragma unroll
    for (int fm = 0; fm < 4; ++fm)
#pragma unroll
      for (int fn = 0; fn < 2; ++fn)
        o[fm][fn] = __builtin_amdgcn_mfma_f32_16x16x32_bf16(
            pa[fm], bv[fn], o[fm][fn], 0, 0, 0);
    __builtin_amdgcn_s_setprio(0);
  }
  u16* ob = outp + (size_t)w * 49 * 384 + h * 32;
#pragma unroll
  for (int fm = 0; fm < 4; ++fm) {
#pragma unroll
    for (int r = 0; r < 4; ++r) {
      const int i = fm * 16 + l4 * 4 + r;
      if (i < 49) {
        const float inv = 1.0f / sums[i];
        ob[(size_t)i * 384 + l15] = f2bf(o[fm][0][r] * inv);
        ob[(size_t)i * 384 + 16 + l15] = f2bf(o[fm][1][r] * inv);
      }
    }
  }
}

// ---------------------------------------------------------------------------
extern "C" void kernel_launch(void* const* d_in, const int* in_sizes, int n_in,
                              void* d_out, int out_size, void* d_ws,
                              size_t ws_size, hipStream_t stream) {
  const float* x      = (const float*)d_in[0];
  const float* n1g    = (const float*)d_in[1];
  const float* n1b    = (const float*)d_in[2];
  const float* qkv_w  = (const float*)d_in[3];
  const float* qkv_b  = (const float*)d_in[4];
  const float* tau    = (const float*)d_in[5];
  const float* proj_w = (const float*)d_in[6];
  const float* proj_b = (const float*)d_in[7];
  const float* c_w1   = (const float*)d_in[8];
  const float* c_b1   = (const float*)d_in[9];
  const float* c_w2   = (const float*)d_in[10];
  const float* c_b2   = (const float*)d_in[11];
  const float* n2g    = (const float*)d_in[12];
  const float* n2b    = (const float*)d_in[13];
  const float* mlp_w1 = (const float*)d_in[14];
  const float* mlp_b1 = (const float*)d_in[15];
  const float* mlp_w2 = (const float*)d_in[16];
  const float* mlp_b2 = (const float*)d_in[17];
  float* out = (float*)d_out;
  char* ws = (char*)d_ws;

  // ws layout (bytes)
  constexpr size_t WS_WT    = 0;          // bf16 weights^T, 3538944 B
  constexpr size_t WS_BIAST = 3538944;    // f32 [12][49][49]
  constexpr size_t WS_XW    = 4194304;    // bf16 [100352][384]  (also ln2)
  constexpr size_t WS_QKV   = 81264640;   // bf16 [100352][1152] (also hidden lo)
  constexpr size_t WS_ATT   = 312475648;  // bf16 [100352][384]  (also hidden hi)
  constexpr size_t WS_NEED  = 389545984;

  if (ws_size < WS_NEED) {  // distinctive sentinel: absmax ~12345 => ws too small
    fill_k<<<(out_size + 255) / 256, 256, 0, stream>>>(out, out_size);
    return;
  }

  u16* wqkvT  = (u16*)(ws + WS_WT);
  u16* wprojT = (u16*)(ws + WS_WT + 884736);
  u16* wm1T   = (u16*)(ws + WS_WT + 1179648);
  u16* wm2T   = (u16*)(ws + WS_WT + 2359296);
  float* biasT = (float*)(ws + WS_BIAST);
  u16* xw  = (u16*)(ws + WS_XW);
  u16* qkv = (u16*)(ws + WS_QKV);
  u16* att = (u16*)(ws + WS_ATT);
  u16* hid = qkv;   // [100352][1536] spans qkv+att regions exactly
  u16* ln2 = xw;

  wconv_k<<<6912, 256, 0, stream>>>(qkv_w, proj_w, mlp_w1, mlp_w2, (u16*)ws);
  biastab_k<<<10, 256, 0, stream>>>(c_w1, c_b1, c_w2, c_b2, biasT);
  ln_k<1><<<25088, 256, 0, stream>>>(x, n1g, n1b, xw);
  gemm_k<0, 384><<<dim3(9, 784), 256, 0, stream>>>(xw, wqkvT, qkv_b, tau, qkv,
                                                   100352, 1152);
  attn_k<<<6144, 256, 0, stream>>>(qkv, biasT, att);
  gemm_k<1, 384><<<dim3(3, 784), 256, 0, stream>>>(att, wprojT, proj_b, x, out,
                                                   100352, 384);
  ln_k<0><<<25088, 256, 0, stream>>>(out, n2g, n2b, ln2);
  gemm_k<2, 384><<<dim3(12, 784), 256, 0, stream>>>(ln2, wm1T, mlp_b1, nullptr,
                                                    hid, 100352, 1536);
  gemm_k<3, 1536><<<dim3(3, 784), 256, 0, stream>>>(hid, wm2T, mlp_b2, nullptr,
                                                    out, 100352, 384);
}